// Round 1
// baseline (21.482 us; speedup 1.0000x reference)
//
#include <hip/hip_runtime.h>

#define BB 4
#define LL 1024
#define NPOS (BB*LL)
#define TI 16

__device__ inline void ffn4(float x, const float* __restrict__ W1, const float* __restrict__ b1,
                            const float* __restrict__ W2, const float* __restrict__ b2, float out[4]) {
    float h[4];
#pragma unroll
    for (int d = 0; d < 4; ++d) h[d] = fmaxf(fmaf(x, W1[d], b1[d]), 0.0f);
#pragma unroll
    for (int j = 0; j < 4; ++j) {
        float a = b2[j];
#pragma unroll
        for (int d = 0; d < 4; ++d) a = fmaf(h[d], W2[d * 4 + j], a);
        out[j] = fmaxf(a, 0.0f);
    }
}

// One thread per (b,l) position: run the 3 tiny FFNs, precompute
// cos/sin(2*pi*pv*x), sqrt(sg+eps), (sg+eps)^2, basis values.
__global__ void precompute_kernel(const float* __restrict__ t,
    const float* __restrict__ Wp1, const float* __restrict__ bp1,
    const float* __restrict__ Wp2, const float* __restrict__ bp2,
    const float* __restrict__ Ws1, const float* __restrict__ bs1,
    const float* __restrict__ Ws2, const float* __restrict__ bs2,
    const float* __restrict__ Wb1, const float* __restrict__ bb1,
    const float* __restrict__ Wb2, const float* __restrict__ bb2,
    float4* __restrict__ qc, float4* __restrict__ qs, float4* __restrict__ ra,
    float4* __restrict__ s2, float4* __restrict__ be)
{
    int p = blockIdx.x * blockDim.x + threadIdx.x;
    if (p >= NPOS) return;
    float x = t[p];
    float pv[4], sg[4], bv[4];
    ffn4(x, Wp1, bp1, Wp2, bp2, pv);
    ffn4(x, Ws1, bs1, Ws2, bs2, sg);
    ffn4(x, Wb1, bb1, Wb2, bb2, bv);
    float qcv[4], qsv[4], rav[4], s2v[4];
#pragma unroll
    for (int d = 0; d < 4; ++d) {
        float qp = 6.283185307179586f * pv[d] * x;
        qcv[d] = cosf(qp);
        qsv[d] = sinf(qp);
        float sq = sg[d] + 1e-6f;
        rav[d] = sqrtf(sq);
        s2v[d] = sq * sq;
    }
    qc[p] = make_float4(qcv[0], qcv[1], qcv[2], qcv[3]);
    qs[p] = make_float4(qsv[0], qsv[1], qsv[2], qsv[3]);
    ra[p] = make_float4(rav[0], rav[1], rav[2], rav[3]);
    s2[p] = make_float4(s2v[0], s2v[1], s2v[2], s2v[3]);
    be[p] = make_float4(bv[0], bv[1], bv[2], bv[3]);
}

__device__ inline float term(float td2, float s2i, float s2j, float rai, float raj,
                             float qci, float qcj, float qsi, float qsj,
                             float bei, float bej) {
    float denom = s2i + s2j;            // sq^2 + sk^2
    float rs = rsqrtf(denom);
    float e = __expf(-td2 * rs * rs);   // exp(-td2/denom)
    float lc = 1.41421356237f * rai * raj * rs;  // sqrt(2*sq*sk/denom)
    float cv = fmaf(qci, qcj, qsi * qsj);        // cos(qp_i - qp_j)
    return bei * bej * lc * e * cv;
}

__global__ __launch_bounds__(256) void pair_kernel(const float* __restrict__ t,
    const float4* __restrict__ qc, const float4* __restrict__ qs,
    const float4* __restrict__ ra, const float4* __restrict__ s2,
    const float4* __restrict__ be, float* __restrict__ out)
{
    __shared__ float  sh_t[TI];
    __shared__ float4 sh_qc[TI], sh_qs[TI], sh_ra[TI], sh_s2[TI], sh_be[TI];

    const int b  = blockIdx.z;
    const int i0 = blockIdx.y * TI;
    const int j  = blockIdx.x * 256 + threadIdx.x;

    if (threadIdx.x < TI) {
        int p = b * LL + i0 + threadIdx.x;
        sh_t[threadIdx.x]  = t[p];
        sh_qc[threadIdx.x] = qc[p];
        sh_qs[threadIdx.x] = qs[p];
        sh_ra[threadIdx.x] = ra[p];
        sh_s2[threadIdx.x] = s2[p];
        sh_be[threadIdx.x] = be[p];
    }
    __syncthreads();

    const int pj = b * LL + j;
    const float tj = t[pj];
    const float4 qcj = qc[pj], qsj = qs[pj], raj = ra[pj], s2j = s2[pj], bej = be[pj];

    float* orow = out + ((size_t)b * LL + i0) * LL + j;

#pragma unroll 4
    for (int ii = 0; ii < TI; ++ii) {
        float td  = sh_t[ii] - tj;
        float td2 = td * td;
        float4 qci = sh_qc[ii], qsi = sh_qs[ii], rai = sh_ra[ii],
               s2i = sh_s2[ii], bei = sh_be[ii];
        float acc =
            term(td2, s2i.x, s2j.x, rai.x, raj.x, qci.x, qcj.x, qsi.x, qsj.x, bei.x, bej.x) +
            term(td2, s2i.y, s2j.y, rai.y, raj.y, qci.y, qcj.y, qsi.y, qsj.y, bei.y, bej.y) +
            term(td2, s2i.z, s2j.z, rai.z, raj.z, qci.z, qcj.z, qsi.z, qsj.z, bei.z, bej.z) +
            term(td2, s2i.w, s2j.w, rai.w, raj.w, qci.w, qcj.w, qsi.w, qsj.w, bei.w, bej.w);
        orow[(size_t)ii * LL] = acc;
    }
}

extern "C" void kernel_launch(void* const* d_in, const int* in_sizes, int n_in,
                              void* d_out, int out_size, void* d_ws, size_t ws_size,
                              hipStream_t stream) {
    const float* t   = (const float*)d_in[0];
    const float* Wp1 = (const float*)d_in[1];
    const float* bp1 = (const float*)d_in[2];
    const float* Wp2 = (const float*)d_in[3];
    const float* bp2 = (const float*)d_in[4];
    const float* Ws1 = (const float*)d_in[5];
    const float* bs1 = (const float*)d_in[6];
    const float* Ws2 = (const float*)d_in[7];
    const float* bs2 = (const float*)d_in[8];
    const float* Wb1 = (const float*)d_in[9];
    const float* bb1 = (const float*)d_in[10];
    const float* Wb2 = (const float*)d_in[11];
    const float* bb2 = (const float*)d_in[12];
    float* out = (float*)d_out;

    float4* qc = (float4*)d_ws;
    float4* qs = qc + NPOS;
    float4* ra = qs + NPOS;
    float4* s2 = ra + NPOS;
    float4* be = s2 + NPOS;

    hipLaunchKernelGGL(precompute_kernel, dim3(NPOS / 256), dim3(256), 0, stream,
                       t, Wp1, bp1, Wp2, bp2, Ws1, bs1, Ws2, bs2, Wb1, bb1, Wb2, bb2,
                       qc, qs, ra, s2, be);

    dim3 grid(LL / 256, LL / TI, BB);  // (j-tiles, i-tiles, batch)
    hipLaunchKernelGGL(pair_kernel, grid, dim3(256), 0, stream,
                       t, qc, qs, ra, s2, be, out);
}

// Round 2
// 18.298 us; speedup vs baseline: 1.1740x; 1.1740x over previous
//
#include <hip/hip_runtime.h>

#define BB 4
#define LL 1024
#define TI 16

__device__ __forceinline__ void ffn4(float x,
    const float* __restrict__ W1, const float* __restrict__ b1,
    const float* __restrict__ W2, const float* __restrict__ b2, float out[4]) {
    float h[4];
#pragma unroll
    for (int d = 0; d < 4; ++d) h[d] = fmaxf(fmaf(x, W1[d], b1[d]), 0.0f);
#pragma unroll
    for (int j = 0; j < 4; ++j) {
        float a = b2[j];
#pragma unroll
        for (int d = 0; d < 4; ++d) a = fmaf(h[d], W2[d * 4 + j], a);
        out[j] = fmaxf(a, 0.0f);
    }
}

// Per-position derived quantities for the pair formula:
//   qc,qs = cos/sin(2*pi*pv*x); s2 = (sg+eps)^2; f = be*sqrt(sg+eps)
__device__ __forceinline__ void position_data(float x,
    const float* __restrict__ Wp1, const float* __restrict__ bp1,
    const float* __restrict__ Wp2, const float* __restrict__ bp2,
    const float* __restrict__ Ws1, const float* __restrict__ bs1,
    const float* __restrict__ Ws2, const float* __restrict__ bs2,
    const float* __restrict__ Wb1, const float* __restrict__ bb1,
    const float* __restrict__ Wb2, const float* __restrict__ bb2,
    float qc[4], float qs[4], float s2[4], float f[4])
{
    float pv[4], sg[4], bv[4];
    ffn4(x, Wp1, bp1, Wp2, bp2, pv);
    ffn4(x, Ws1, bs1, Ws2, bs2, sg);
    ffn4(x, Wb1, bb1, Wb2, bb2, bv);
#pragma unroll
    for (int d = 0; d < 4; ++d) {
        float qp = 6.283185307179586f * pv[d] * x;
        float s, c;
        __sincosf(qp, &s, &c);
        qc[d] = c; qs[d] = s;
        float sq = sg[d] + 1e-6f;
        s2[d] = sq * sq;
        f[d]  = bv[d] * sqrtf(sq);
    }
}

__global__ __launch_bounds__(256) void fused_kernel(const float* __restrict__ t,
    const float* __restrict__ Wp1, const float* __restrict__ bp1,
    const float* __restrict__ Wp2, const float* __restrict__ bp2,
    const float* __restrict__ Ws1, const float* __restrict__ bs1,
    const float* __restrict__ Ws2, const float* __restrict__ bs2,
    const float* __restrict__ Wb1, const float* __restrict__ bb1,
    const float* __restrict__ Wb2, const float* __restrict__ bb2,
    float* __restrict__ out)
{
    __shared__ float sh_t[TI];
    __shared__ float sh_qc[4][TI], sh_qs[4][TI], sh_s2[4][TI], sh_f[4][TI];

    const int tid = threadIdx.x;
    const int b   = blockIdx.z;
    const int i0  = blockIdx.y * TI;
    const int j   = blockIdx.x * 256 + tid;

    // --- i-tile into LDS (threads 0..15) ---
    if (tid < TI) {
        float xi = t[b * LL + i0 + tid];
        float qc[4], qs[4], s2[4], f[4];
        position_data(xi, Wp1, bp1, Wp2, bp2, Ws1, bs1, Ws2, bs2,
                      Wb1, bb1, Wb2, bb2, qc, qs, s2, f);
        sh_t[tid] = xi;
#pragma unroll
        for (int d = 0; d < 4; ++d) {
            sh_qc[d][tid] = qc[d];
            sh_qs[d][tid] = qs[d];
            sh_s2[d][tid] = s2[d];
            sh_f[d][tid]  = f[d];
        }
    }

    // --- per-thread j data in registers ---
    const float xj = t[b * LL + j];
    float qcj[4], qsj[4], s2j[4], fj[4];
    position_data(xj, Wp1, bp1, Wp2, bp2, Ws1, bs1, Ws2, bs2,
                  Wb1, bb1, Wb2, bb2, qcj, qsj, s2j, fj);
#pragma unroll
    for (int d = 0; d < 4; ++d) fj[d] *= 1.41421356237309505f;  // sqrt(2) folded once

    __syncthreads();

    float* orow = out + ((size_t)b * LL + i0) * LL + j;

#pragma unroll 4
    for (int ii = 0; ii < TI; ++ii) {
        float td  = sh_t[ii] - xj;
        float td2 = td * td;
        float acc = 0.0f;
#pragma unroll
        for (int d = 0; d < 4; ++d) {
            float denom = sh_s2[d][ii] + s2j[d];
            float rs = rsqrtf(denom);
            float e  = __expf(-td2 * rs * rs);               // exp(-td2/denom)
            float cv = fmaf(sh_qc[d][ii], qcj[d], sh_qs[d][ii] * qsj[d]);
            acc = fmaf(sh_f[d][ii] * fj[d], rs * e * cv, acc);
        }
        orow[(size_t)ii * LL] = acc;
    }
}

extern "C" void kernel_launch(void* const* d_in, const int* in_sizes, int n_in,
                              void* d_out, int out_size, void* d_ws, size_t ws_size,
                              hipStream_t stream) {
    const float* t   = (const float*)d_in[0];
    const float* Wp1 = (const float*)d_in[1];
    const float* bp1 = (const float*)d_in[2];
    const float* Wp2 = (const float*)d_in[3];
    const float* bp2 = (const float*)d_in[4];
    const float* Ws1 = (const float*)d_in[5];
    const float* bs1 = (const float*)d_in[6];
    const float* Ws2 = (const float*)d_in[7];
    const float* bs2 = (const float*)d_in[8];
    const float* Wb1 = (const float*)d_in[9];
    const float* bb1 = (const float*)d_in[10];
    const float* Wb2 = (const float*)d_in[11];
    const float* bb2 = (const float*)d_in[12];
    float* out = (float*)d_out;

    dim3 grid(LL / 256, LL / TI, BB);  // (j-strips, i-tiles, batch) = (4,64,4)
    hipLaunchKernelGGL(fused_kernel, grid, dim3(256), 0, stream,
                       t, Wp1, bp1, Wp2, bp2, Ws1, bs1, Ws2, bs2,
                       Wb1, bb1, Wb2, bb2, out);
}

// Round 3
// 16.596 us; speedup vs baseline: 1.2945x; 1.1026x over previous
//
#include <hip/hip_runtime.h>

#define BB 4
#define LL 1024
#define TI 16
// each thread computes 2 consecutive j columns; block covers 512 j's
// grid = (LL/512, LL/TI, BB) = (2, 64, 4) = 512 blocks -> 2 blocks/CU

typedef float f32x2 __attribute__((ext_vector_type(2)));
typedef float f32x4 __attribute__((ext_vector_type(4)));

__device__ __forceinline__ void ffn4(float x,
    const float* __restrict__ W1, const float* __restrict__ b1,
    const float* __restrict__ W2, const float* __restrict__ b2, float out[4]) {
    float h[4];
#pragma unroll
    for (int d = 0; d < 4; ++d) h[d] = fmaxf(fmaf(x, W1[d], b1[d]), 0.0f);
#pragma unroll
    for (int j = 0; j < 4; ++j) {
        float a = b2[j];
#pragma unroll
        for (int d = 0; d < 4; ++d) a = fmaf(h[d], W2[d * 4 + j], a);
        out[j] = fmaxf(a, 0.0f);
    }
}

// Per-position derived data, basis factor folded into cos/sin:
//   s2 = (sg+eps)^2 ; c = f*cos(2pi*pv*x) ; s = f*sin(2pi*pv*x)
//   where f = be*sqrt(sg+eps) * (sqrt(2) if R2)
template<bool R2>
__device__ __forceinline__ void posdata(float x,
    const float* __restrict__ Wp1, const float* __restrict__ bp1,
    const float* __restrict__ Wp2, const float* __restrict__ bp2,
    const float* __restrict__ Ws1, const float* __restrict__ bs1,
    const float* __restrict__ Ws2, const float* __restrict__ bs2,
    const float* __restrict__ Wb1, const float* __restrict__ bb1,
    const float* __restrict__ Wb2, const float* __restrict__ bb2,
    f32x4& s2o, f32x4& co, f32x4& so)
{
    float pv[4], sg[4], bv[4];
    ffn4(x, Wp1, bp1, Wp2, bp2, pv);
    ffn4(x, Ws1, bs1, Ws2, bs2, sg);
    ffn4(x, Wb1, bb1, Wb2, bb2, bv);
#pragma unroll
    for (int d = 0; d < 4; ++d) {
        float qp = 6.283185307179586f * pv[d] * x;
        float s, c;
        __sincosf(qp, &s, &c);
        float sq = sg[d] + 1e-6f;
        float f  = bv[d] * sqrtf(sq);
        if (R2) f *= 1.41421356237309505f;
        s2o[d] = sq * sq;
        co[d]  = f * c;
        so[d]  = f * s;
    }
}

// one d-pair (2 of the 4 feature dims), packed f32 math
__device__ __forceinline__ f32x2 pair_term(f32x2 s2i, f32x2 s2j,
                                           f32x2 ci, f32x2 cj,
                                           f32x2 si, f32x2 sj,
                                           f32x2 ntd2, f32x2 acc)
{
    f32x2 den = s2i + s2j;
    f32x2 rs; rs.x = rsqrtf(den.x); rs.y = rsqrtf(den.y);
    f32x2 rs2 = rs * rs;
    f32x2 arg = ntd2 * rs2;
    f32x2 e; e.x = __expf(arg.x); e.y = __expf(arg.y);
    f32x2 cv = __builtin_elementwise_fma(ci, cj, si * sj);
    f32x2 m = rs * e;
    return __builtin_elementwise_fma(m, cv, acc);
}

__global__ __launch_bounds__(256) void fused_kernel(const float* __restrict__ t,
    const float* __restrict__ Wp1, const float* __restrict__ bp1,
    const float* __restrict__ Wp2, const float* __restrict__ bp2,
    const float* __restrict__ Ws1, const float* __restrict__ bs1,
    const float* __restrict__ Ws2, const float* __restrict__ bs2,
    const float* __restrict__ Wb1, const float* __restrict__ bb1,
    const float* __restrict__ Wb2, const float* __restrict__ bb2,
    float* __restrict__ out)
{
    __shared__ f32x4 sh_s2[TI], sh_c[TI], sh_s[TI];
    __shared__ float sh_t[TI];

    const int tid = threadIdx.x;
    const int b   = blockIdx.z;
    const int i0  = blockIdx.y * TI;
    const int j0  = blockIdx.x * 512 + tid * 2;   // this thread's 2 columns

    // --- i-tile into LDS (threads 0..15), sqrt(2) folded here ---
    if (tid < TI) {
        float xi = t[b * LL + i0 + tid];
        f32x4 s2i, ci, si;
        posdata<true>(xi, Wp1, bp1, Wp2, bp2, Ws1, bs1, Ws2, bs2,
                      Wb1, bb1, Wb2, bb2, s2i, ci, si);
        sh_t[tid]  = xi;
        sh_s2[tid] = s2i;
        sh_c[tid]  = ci;
        sh_s[tid]  = si;
    }

    // --- per-thread j data (2 columns) in registers ---
    float tj0 = t[b * LL + j0];
    float tj1 = t[b * LL + j0 + 1];
    f32x4 s2j[2], cj[2], sj[2];
    posdata<false>(tj0, Wp1, bp1, Wp2, bp2, Ws1, bs1, Ws2, bs2,
                   Wb1, bb1, Wb2, bb2, s2j[0], cj[0], sj[0]);
    posdata<false>(tj1, Wp1, bp1, Wp2, bp2, Ws1, bs1, Ws2, bs2,
                   Wb1, bb1, Wb2, bb2, s2j[1], cj[1], sj[1]);

    __syncthreads();

    float* obase = out + ((size_t)b * LL + i0) * LL + j0;

#pragma unroll 4
    for (int ii = 0; ii < TI; ++ii) {
        f32x4 s2i = sh_s2[ii], ci = sh_c[ii], si = sh_s[ii];
        float tiv = sh_t[ii];
        float res[2];
#pragma unroll
        for (int jj = 0; jj < 2; ++jj) {
            float td = tiv - (jj ? tj1 : tj0);
            float n = -(td * td);
            f32x2 ntd2; ntd2.x = n; ntd2.y = n;
            f32x2 acc; acc.x = 0.0f; acc.y = 0.0f;
            f32x2 s2i_lo; s2i_lo.x = s2i[0]; s2i_lo.y = s2i[1];
            f32x2 s2i_hi; s2i_hi.x = s2i[2]; s2i_hi.y = s2i[3];
            f32x2 ci_lo;  ci_lo.x  = ci[0];  ci_lo.y  = ci[1];
            f32x2 ci_hi;  ci_hi.x  = ci[2];  ci_hi.y  = ci[3];
            f32x2 si_lo;  si_lo.x  = si[0];  si_lo.y  = si[1];
            f32x2 si_hi;  si_hi.x  = si[2];  si_hi.y  = si[3];
            f32x2 s2j_lo; s2j_lo.x = s2j[jj][0]; s2j_lo.y = s2j[jj][1];
            f32x2 s2j_hi; s2j_hi.x = s2j[jj][2]; s2j_hi.y = s2j[jj][3];
            f32x2 cj_lo;  cj_lo.x  = cj[jj][0];  cj_lo.y  = cj[jj][1];
            f32x2 cj_hi;  cj_hi.x  = cj[jj][2];  cj_hi.y  = cj[jj][3];
            f32x2 sj_lo;  sj_lo.x  = sj[jj][0];  sj_lo.y  = sj[jj][1];
            f32x2 sj_hi;  sj_hi.x  = sj[jj][2];  sj_hi.y  = sj[jj][3];
            acc = pair_term(s2i_lo, s2j_lo, ci_lo, cj_lo, si_lo, sj_lo, ntd2, acc);
            acc = pair_term(s2i_hi, s2j_hi, ci_hi, cj_hi, si_hi, sj_hi, ntd2, acc);
            res[jj] = acc.x + acc.y;
        }
        *reinterpret_cast<float2*>(obase + (size_t)ii * LL) = make_float2(res[0], res[1]);
    }
}

extern "C" void kernel_launch(void* const* d_in, const int* in_sizes, int n_in,
                              void* d_out, int out_size, void* d_ws, size_t ws_size,
                              hipStream_t stream) {
    const float* t   = (const float*)d_in[0];
    const float* Wp1 = (const float*)d_in[1];
    const float* bp1 = (const float*)d_in[2];
    const float* Wp2 = (const float*)d_in[3];
    const float* bp2 = (const float*)d_in[4];
    const float* Ws1 = (const float*)d_in[5];
    const float* bs1 = (const float*)d_in[6];
    const float* Ws2 = (const float*)d_in[7];
    const float* bs2 = (const float*)d_in[8];
    const float* Wb1 = (const float*)d_in[9];
    const float* bb1 = (const float*)d_in[10];
    const float* Wb2 = (const float*)d_in[11];
    const float* bb2 = (const float*)d_in[12];
    float* out = (float*)d_out;

    dim3 grid(LL / 512, LL / TI, BB);  // (2, 64, 4)
    hipLaunchKernelGGL(fused_kernel, grid, dim3(256), 0, stream,
                       t, Wp1, bp1, Wp2, bp2, Ws1, bs1, Ws2, bs2,
                       Wb1, bb1, Wb2, bb2, out);
}